// Round 9
// baseline (40.142 us; speedup 1.0000x reference)
//
#include <hip/hip_runtime.h>

// DiffNet, single dispatch, 3 layers, DUAL-STREAM barrier hiding.
// Math (exact collapse of the two 1x1 convs -- affine in meta):
//   Wv = vi @ W.T (pre-bias), vj = relu(Wv + b)
//   A_c = sum_h c2w[h]*c1w[h][c],  D = sum_h c2w[h]*c1b[h] + c2b
//   s1 = sum_i vi, s2 = sum_i vi^2 (per row)
//   delta = scale*(A0*s2 + A1*Wv + (A2*vj + D)*s1),  out = vj + delta
//
// Decomposition: 4 row-domains of 8 batch rows. Block set s (16 blocks, 512
// threads) owns domains A=2s, B=2s+1 with IDENTICAL column assignment (weights
// shared in registers). Schedule interleaves the two independent streams so
// each domain-barrier WAIT hides behind the other stream's compute:
//   P1A arriveA P1B arriveB [waitA] P2A arriveA [waitB] P2B arriveB [waitA] P3A [waitB] P3B
// Inter-phase t1/t2 via relaxed AGENT-scope atomics (L3-coherent, no fences).
// Barrier: per-domain monotonic counter (16 arrivals) + epoch flag in
// zero-initialized __device__ globals -- self-cleaning, no per-launch reset,
// deterministic across graph replays.

#define NSET 2
#define BPS  16                    // blocks per set = arrivals per barrier
#define NBLK (NSET * BPS)
#define NDOM 4

__device__ unsigned int g_cnt[NDOM * 32];    // arrival counters, 128B apart
__device__ unsigned int g_flag[NDOM * 32];   // epoch flags, 128B apart

__device__ __forceinline__ void bar_arrive(int dom, unsigned int target) {
    __syncthreads();   // all waves drain their global stores at barrier entry
    if (threadIdx.x == 0) {
        asm volatile("s_waitcnt vmcnt(0)" ::: "memory");
        unsigned int old = __hip_atomic_fetch_add(&g_cnt[dom * 32], 1u,
                               __ATOMIC_RELAXED, __HIP_MEMORY_SCOPE_AGENT);
        if ((old & (BPS - 1u)) == (BPS - 1u))
            __hip_atomic_store(&g_flag[dom * 32], target,      // single writer
                               __ATOMIC_RELAXED, __HIP_MEMORY_SCOPE_AGENT);
    }
}

__device__ __forceinline__ void bar_wait(int dom, unsigned int target) {
    if (threadIdx.x == 0) {
        while ((int)(__hip_atomic_load(&g_flag[dom * 32], __ATOMIC_RELAXED,
                                       __HIP_MEMORY_SCOPE_AGENT) - target) < 0)
            __builtin_amdgcn_s_sleep(1);
        asm volatile("" ::: "memory");
    }
    __syncthreads();
}

__device__ __forceinline__ float pairred(float a, float b, int lane) {
    const float u = a + __shfl_xor(a, 1);
    const float w = b + __shfl_xor(b, 1);
    return (lane & 1) ? w : u;
}

template<int IIN, int CPW>
__device__ __forceinline__ void wprefetch(const float* __restrict__ W,
                                          const float* __restrict__ bias,
                                          int c0, int lane,
                                          float4 (&wr)[CPW][IIN / 256],
                                          float (&bs)[CPW]) {
    #pragma unroll
    for (int cc = 0; cc < CPW; ++cc) {
        const float4* Wr = reinterpret_cast<const float4*>(W + (size_t)(c0 + cc) * IIN);
        #pragma unroll
        for (int q = 0; q < IIN / 256; ++q) wr[cc][q] = Wr[q * 64 + lane];
        bs[cc] = bias[c0 + cc];
    }
}

// 8 rows staged in LDS; 8 waves; CPW columns per wave (weights in registers).
// AIN:  stage via relaxed agent atomic u64 loads (L3-coherent)
// AOUT: write via relaxed agent atomic f32 stores
template<int IIN, int OUT, int CPW, bool AIN, bool AOUT>
__device__ __forceinline__ void phase(const float* __restrict__ vin,   // row-0 base
                                      const float4 (&wr)[CPW][IIN / 256],
                                      const float (&bs)[CPW],
                                      float* __restrict__ vout,        // [32, OUT]
                                      float* __restrict__ lds,
                                      float* __restrict__ s1s,
                                      float* __restrict__ s2s,
                                      int rows0, int c0, int lane, int wave,
                                      float A0, float A1, float A2,
                                      float Dd, float scale)
{
    constexpr int ROWS = 8;

    // ---- stage 8 x IIN rows into LDS (512 threads) ----
    if (AIN) {
        const unsigned long long* src = reinterpret_cast<const unsigned long long*>(
            vin + (size_t)rows0 * IIN);
        float2* dst = reinterpret_cast<float2*>(lds);
        constexpr int N2 = ROWS * IIN / 2;
        #pragma unroll
        for (int k = 0; k < N2 / 512; ++k) {
            unsigned long long u = __hip_atomic_load(
                &src[k * 512 + threadIdx.x], __ATOMIC_RELAXED, __HIP_MEMORY_SCOPE_AGENT);
            float2 f;
            __builtin_memcpy(&f, &u, 8);
            dst[k * 512 + threadIdx.x] = f;
        }
    } else {
        const float4* src = reinterpret_cast<const float4*>(vin + (size_t)rows0 * IIN);
        float4* dst = reinterpret_cast<float4*>(lds);
        constexpr int N4 = ROWS * IIN / 4;
        #pragma unroll
        for (int k = 0; k < N4 / 512; ++k)
            dst[k * 512 + threadIdx.x] = src[k * 512 + threadIdx.x];
    }
    __syncthreads();

    // ---- per-row s1, s2: wave w owns row w ----
    {
        const float4* v4 = reinterpret_cast<const float4*>(lds + wave * IIN);
        float p1 = 0.f, p2 = 0.f;
        #pragma unroll
        for (int q = 0; q < IIN / 256; ++q) {
            const float4 a = v4[q * 64 + lane];
            p1 += (a.x + a.y) + (a.z + a.w);
            p2 += a.x * a.x + a.y * a.y + a.z * a.z + a.w * a.w;
        }
        #pragma unroll
        for (int s = 32; s > 0; s >>= 1) {
            p1 += __shfl_xor(p1, s);
            p2 += __shfl_xor(p2, s);
        }
        if (lane == 0) { s1s[wave] = p1; s2s[wave] = p2; }
    }

    // ---- dots: CPW columns per wave vs 8 staged rows ----
    float acc[CPW][ROWS];
    #pragma unroll
    for (int c = 0; c < CPW; ++c)
        #pragma unroll
        for (int r = 0; r < ROWS; ++r) acc[c][r] = 0.f;

    #pragma unroll
    for (int q = 0; q < IIN / 256; ++q) {
        float4 w[CPW];
        #pragma unroll
        for (int c = 0; c < CPW; ++c) w[c] = wr[c][q];
        #pragma unroll
        for (int r = 0; r < ROWS; ++r) {
            const float4 v = *reinterpret_cast<const float4*>(
                lds + r * IIN + (q * 64 + lane) * 4);
            #pragma unroll
            for (int c = 0; c < CPW; ++c)
                acc[c][r] = fmaf(w[c].w, v.w, fmaf(w[c].z, v.z,
                            fmaf(w[c].y, v.y, fmaf(w[c].x, v.x, acc[c][r]))));
        }
    }

    // ---- reduce; lane (r*CPW + cc) gathers (row r, col c0+cc) ----
    float Wv = 0.f;
    #pragma unroll
    for (int r = 0; r < ROWS; ++r) {
        float z0 = pairred(acc[0][r], acc[1][r], lane);
        float z1 = 0.f;
        if (CPW == 4) z1 = pairred(acc[2][r], acc[3][r], lane);
        #pragma unroll
        for (int s = 2; s < 64; s <<= 1) {
            z0 += __shfl_xor(z0, s);
            if (CPW == 4) z1 += __shfl_xor(z1, s);
        }
        if (CPW == 4) {
            if ((lane >> 2) == r) Wv = (lane & 2) ? z1 : z0;
        } else {
            if ((lane >> 1) == r) Wv = z0;
        }
    }

    __syncthreads();   // all waves' s1s/s2s visible before epilogue

    // ---- epilogue ----
    if (lane < ROWS * CPW) {
        const int row = lane / CPW;
        const int cc  = lane & (CPW - 1);
        float biasv;
        if (CPW == 4)
            biasv = (lane & 2) ? ((lane & 1) ? bs[3] : bs[2])
                               : ((lane & 1) ? bs[1] : bs[0]);
        else
            biasv = (lane & 1) ? bs[1] : bs[0];
        const float vj  = fmaxf(Wv + biasv, 0.f);
        const float val = vj + scale * (A0 * s2s[row] + A1 * Wv
                                        + (A2 * vj + Dd) * s1s[row]);
        float* dst = vout + (size_t)(rows0 + row) * OUT + c0 + cc;
        if (AOUT)
            __hip_atomic_store(dst, val, __ATOMIC_RELAXED, __HIP_MEMORY_SCOPE_AGENT);
        else
            *dst = val;
    }
}

__global__ void __launch_bounds__(512, 1)
diffnet_onekernel(const float* __restrict__ x,
                  const float* __restrict__ W1, const float* __restrict__ b1,
                  const float* __restrict__ W2, const float* __restrict__ b2,
                  const float* __restrict__ W3, const float* __restrict__ b3,
                  const float* __restrict__ c1w, const float* __restrict__ c1b,
                  const float* __restrict__ c2w, const float* __restrict__ c2b,
                  const int* __restrict__ bn,
                  float* __restrict__ t1, float* __restrict__ t2,
                  float* __restrict__ out)
{
    __shared__ float lds[8 * 1024];       // 32 KB (phase 1: 8 rows x 1024)
    __shared__ float s1s[8], s2s[8];

    const int bid  = blockIdx.x;
    const int set  = bid >> 4;            // 2 sets x 16 blocks
    const int j    = bid & 15;
    const int domA = set * 2;
    const int domB = set * 2 + 1;
    const int rowsA = domA * 8;
    const int rowsB = domB * 8;
    const int lane = threadIdx.x & 63;
    const int wave = threadIdx.x >> 6;

    // epoch bases (safe: a domain's flag can't advance past this launch's
    // epochs until this block itself arrives)
    unsigned int FA = 0, FB = 0;
    if (threadIdx.x == 0) {
        FA = __hip_atomic_load(&g_flag[domA * 32], __ATOMIC_RELAXED,
                               __HIP_MEMORY_SCOPE_AGENT);
        FB = __hip_atomic_load(&g_flag[domB * 32], __ATOMIC_RELAXED,
                               __HIP_MEMORY_SCOPE_AGENT);
    }

    // collapsed conv constants (uniform scalar loads)
    float A0 = 0.f, A1 = 0.f, A2 = 0.f, Dd = c2b[0];
    #pragma unroll
    for (int h = 0; h < 8; ++h) {
        const float w2 = c2w[h];
        A0 = fmaf(w2, c1w[h * 3 + 0], A0);
        A1 = fmaf(w2, c1w[h * 3 + 1], A1);
        A2 = fmaf(w2, c1w[h * 3 + 2], A2);
        Dd = fmaf(w2, c1b[h], Dd);
    }
    const int raw = bn[0];
    const float bnf = (raw > 0 && raw < 1000000) ? (float)raw : __int_as_float(raw);
    const float scale = 0.1f / bnf;

    const int c12 = j * 32 + wave * 4;    // phases 1/2: 32 cols/block, 4/wave
    const int c3  = j * 16 + wave * 2;    // phase 3:    16 cols/block, 2/wave

    // ---- phase 1 weights (shared by streams A and B) ----
    float4 w1r[4][4];
    float  b1s[4];
    wprefetch<1024, 4>(W1, b1, c12, lane, w1r, b1s);

    // P1A, P1B
    phase<1024, 512, 4, false, true>(x, w1r, b1s, t1, lds, s1s, s2s,
                                     rowsA, c12, lane, wave, A0, A1, A2, Dd, scale);
    bar_arrive(domA, FA + 1);
    phase<1024, 512, 4, false, true>(x, w1r, b1s, t1, lds, s1s, s2s,
                                     rowsB, c12, lane, wave, A0, A1, A2, Dd, scale);
    bar_arrive(domB, FB + 1);

    // phase-2 weights: issue while waiting for A's flag
    float4 w2r[4][2];
    float  b2s[4];
    wprefetch<512, 4>(W2, b2, c12, lane, w2r, b2s);

    bar_wait(domA, FA + 1);
    phase<512, 512, 4, true, true>(t1, w2r, b2s, t2, lds, s1s, s2s,
                                   rowsA, c12, lane, wave, A0, A1, A2, Dd, scale);
    bar_arrive(domA, FA + 2);

    bar_wait(domB, FB + 1);
    phase<512, 512, 4, true, true>(t1, w2r, b2s, t2, lds, s1s, s2s,
                                   rowsB, c12, lane, wave, A0, A1, A2, Dd, scale);
    bar_arrive(domB, FB + 2);

    // phase-3 weights: issue while waiting for A's flag
    float4 w3r[2][2];
    float  b3s[2];
    wprefetch<512, 2>(W3, b3, c3, lane, w3r, b3s);

    bar_wait(domA, FA + 2);
    phase<512, 256, 2, true, false>(t2, w3r, b3s, out, lds, s1s, s2s,
                                    rowsA, c3, lane, wave, A0, A1, A2, Dd, scale);

    bar_wait(domB, FB + 2);
    phase<512, 256, 2, true, false>(t2, w3r, b3s, out, lds, s1s, s2s,
                                    rowsB, c3, lane, wave, A0, A1, A2, Dd, scale);
}

extern "C" void kernel_launch(void* const* d_in, const int* in_sizes, int n_in,
                              void* d_out, int out_size, void* d_ws, size_t ws_size,
                              hipStream_t stream) {
    const float* x     = (const float*)d_in[0];
    const float* fc1_w = (const float*)d_in[1];
    const float* fc1_b = (const float*)d_in[2];
    const float* fc2_w = (const float*)d_in[3];
    const float* fc2_b = (const float*)d_in[4];
    const float* fc3_w = (const float*)d_in[5];
    const float* fc3_b = (const float*)d_in[6];
    const float* c1w   = (const float*)d_in[7];
    const float* c1b   = (const float*)d_in[8];
    const float* c2w   = (const float*)d_in[9];
    const float* c2b   = (const float*)d_in[10];
    const int*   bn    = (const int*)d_in[11];

    float* t1  = (float*)d_ws;                         // [32, 512] = 64KB
    float* t2  = t1 + 32 * 512;                        // [32, 512] = 64KB
    float* out = (float*)d_out;                        // [32, 256]

    diffnet_onekernel<<<dim3(NBLK), dim3(512), 0, stream>>>(
        x, fc1_w, fc1_b, fc2_w, fc2_b, fc3_w, fc3_b,
        c1w, c1b, c2w, c2b, bn, t1, t2, out);
}